// Round 1
// 1806.879 us; speedup vs baseline: 1.1796x; 1.1796x over previous
//
#include <hip/hip_runtime.h>
#include <stdint.h>

#define BATCH 4
#define HEADS 16
#define SEQ   2048
#define DIM   64
#define QT    32            // q rows per workgroup (2 MFMA m-tiles)
#define KT    64            // k cols per tile (16 per wave)
#define EST   72            // Es row stride elems: 144 B, 16B-aligned, uniform-depth b128 reads

typedef __attribute__((ext_vector_type(8))) short  short8;   // MFMA A/B frag (8 bf16)
typedef __attribute__((ext_vector_type(4))) short  short4v;  // b64 LDS store
typedef __attribute__((ext_vector_type(4))) float  floatx4;  // MFMA C/D frag / vector IO
typedef __attribute__((ext_vector_type(4))) int    intx4;

static __device__ __forceinline__ unsigned short f32_to_bf16_bits(float f) {
    union { float f; uint32_t u; } x; x.f = f;
    uint32_t r = x.u + 0x7FFFu + ((x.u >> 16) & 1u);   // RNE
    return (unsigned short)(r >> 16);
}

__global__ __launch_bounds__(256, 4) void attn_fused_kernel(
    const float* __restrict__ q, const float* __restrict__ k,
    const float* __restrict__ v, const int* __restrict__ mask,
    float* __restrict__ out, float* __restrict__ score)
{
    // Tiny double-buffered E bridge (layout transform QK^T C-frag -> PV B-frag). 9.2 KB total.
    __shared__ __align__(16) unsigned short Es[2][QT][EST];
    __shared__ float lsum[QT];

    const int tid  = threadIdx.x;
    const int w    = tid >> 6;        // wave 0..3 -> 16-col k-slice of the 64-wide tile
    const int lane = tid & 63;
    const int quad = lane >> 4;       // 0..3
    const int nl   = lane & 15;

    const int qt = blockIdx.x;        // 0..63  (q tile) — x-fastest shares K/V/mask in L2
    const int bh = blockIdx.y;        // 0..63  (b*H+h)
    const int b  = bh >> 4;           // H = 16
    const int q0 = qt * QT;

    const float* kbase = k + (size_t)bh * SEQ * DIM;
    const float* vbase = v + (size_t)bh * SEQ * DIM;
    const int*   mbase = mask + ((size_t)b * SEQ + q0) * SEQ;

    if (tid < QT) lsum[tid] = 0.0f;

    // ---- Q B-fragments once per block: aq[mt][s][j] = Q[q0+mt*16+nl][s*32+quad*8+j] ----
    short8 aq[2][2];
    {
        const float* qp = q + ((size_t)bh * SEQ + q0) * DIM;
        #pragma unroll
        for (int mt = 0; mt < 2; ++mt) {
            const float* qrow = qp + (size_t)(mt * 16 + nl) * DIM + quad * 8;
            #pragma unroll
            for (int s = 0; s < 2; ++s) {
                floatx4 f0 = *(const floatx4*)(qrow + s * 32);
                floatx4 f1 = *(const floatx4*)(qrow + s * 32 + 4);
                short8 a;
                #pragma unroll
                for (int j = 0; j < 4; ++j) {
                    a[j]     = (short)f32_to_bf16_bits(f0[j]);
                    a[j + 4] = (short)f32_to_bf16_bits(f1[j]);
                }
                aq[mt][s] = a;
            }
        }
    }

    float   rs[2]   = {0.f, 0.f};
    floatx4 oacc[2] = {{0.f,0.f,0.f,0.f},{0.f,0.f,0.f,0.f}};

    // ============ Pass 1: fused QK^T -> exp -> PV (unnormalized) + rowsums ============
    for (int t = 0; t < SEQ / KT; ++t) {
        const int k0 = t * KT;
        const int p  = t & 1;

        // V frag raw loads issued early (latency hides under QK chain):
        // vraw[s][j] = V[k0+s*32+quad*8+j][w*16+nl]  (coalesced 64B across nl)
        float vraw[2][8];
        {
            const float* vp = vbase + ((size_t)k0 + quad * 8) * DIM + w * 16 + nl;
            #pragma unroll
            for (int s = 0; s < 2; ++s)
                #pragma unroll
                for (int j = 0; j < 8; ++j)
                    vraw[s][j] = vp[(s * 32 + j) * DIM];
        }

        // K frags direct from global (kd contiguous in memory — no LDS needed):
        short8 kf[2];
        {
            const float* krow = kbase + (size_t)(k0 + w * 16 + nl) * DIM + quad * 8;
            #pragma unroll
            for (int s = 0; s < 2; ++s) {
                floatx4 f0 = *(const floatx4*)(krow + s * 32);
                floatx4 f1 = *(const floatx4*)(krow + s * 32 + 4);
                short8 kk;
                #pragma unroll
                for (int j = 0; j < 4; ++j) {
                    kk[j]     = (short)f32_to_bf16_bits(f0[j]);
                    kk[j + 4] = (short)f32_to_bf16_bits(f1[j]);
                }
                kf[s] = kk;
            }
        }

        // mask: int4 per row (4 consecutive k)
        intx4 mr[2];
        #pragma unroll
        for (int mt = 0; mt < 2; ++mt)
            mr[mt] = *(const intx4*)(mbase + (size_t)(mt * 16 + nl) * SEQ + k0 + w * 16 + quad * 4);

        // Swapped QK^T: D[m=k][n=q] -> lane holds S[q=mt*16+nl][k=k0+w*16+quad*4+i]
        floatx4 acc[2] = {{0.f,0.f,0.f,0.f},{0.f,0.f,0.f,0.f}};
        #pragma unroll
        for (int mt = 0; mt < 2; ++mt)
            #pragma unroll
            for (int s = 0; s < 2; ++s)
                acc[mt] = __builtin_amdgcn_mfma_f32_16x16x32_bf16(kf[s], aq[mt][s], acc[mt], 0, 0, 0);

        // E = exp(masked score), rowsum accumulate, stash bf16 tile (b64 stores)
        #pragma unroll
        for (int mt = 0; mt < 2; ++mt) {
            short4v es;
            float esum = 0.f;
            #pragma unroll
            for (int i = 0; i < 4; ++i) {
                float e = (mr[mt][i] != 0) ? __expf(acc[mt][i] * 0.125f) : 1.0f;  // exp(1e-12)==1.0f
                esum += e;
                es[i] = (short)f32_to_bf16_bits(e);
            }
            rs[mt] += esum;
            *(short4v*)&Es[p][mt * 16 + nl][w * 16 + quad * 4] = es;
        }

        __syncthreads();   // Es[p] complete; single barrier/tile (buffers alternate)

        // PV: O += V^T(A-frag) x E(B-frag);  D[m=d][n=q]
        #pragma unroll
        for (int s = 0; s < 2; ++s) {
            short8 vf;
            #pragma unroll
            for (int j = 0; j < 8; ++j)
                vf[j] = (short)f32_to_bf16_bits(vraw[s][j]);
            #pragma unroll
            for (int mt = 0; mt < 2; ++mt) {
                short8 ef = *(const short8*)&Es[p][mt * 16 + nl][s * 32 + quad * 8];
                oacc[mt] = __builtin_amdgcn_mfma_f32_16x16x32_bf16(vf, ef, oacc[mt], 0, 0, 0);
            }
        }
    }

    // ============ rowsum -> reciprocal ============
    #pragma unroll
    for (int mt = 0; mt < 2; ++mt) {
        float x = rs[mt];
        x += __shfl_xor(x, 16);   // sum across quads
        x += __shfl_xor(x, 32);
        if (quad == 0) atomicAdd(&lsum[mt * 16 + nl], x);   // one add per wave per row
    }
    __syncthreads();
    if (tid < QT) lsum[tid] = 1.0f / lsum[tid];
    __syncthreads();
    const float rcp[2] = { lsum[nl], lsum[16 + nl] };

    // ============ O write: lane holds O[q=mt*16+nl][d=w*16+quad*4+i] -> float4 ============
    #pragma unroll
    for (int mt = 0; mt < 2; ++mt) {
        floatx4 o;
        #pragma unroll
        for (int i = 0; i < 4; ++i) o[i] = oacc[mt][i] * rcp[mt];
        *(floatx4*)&out[((size_t)bh * SEQ + q0 + mt * 16 + nl) * DIM + w * 16 + quad * 4] = o;
    }

    // ============ Pass 2: recompute E, write normalized score (barrier-free stream) ============
    float* sb = score + ((size_t)bh * SEQ + q0) * SEQ;
    for (int t = 0; t < SEQ / KT; ++t) {
        const int k0 = t * KT;

        short8 kf[2];
        {
            const float* krow = kbase + (size_t)(k0 + w * 16 + nl) * DIM + quad * 8;
            #pragma unroll
            for (int s = 0; s < 2; ++s) {
                floatx4 f0 = *(const floatx4*)(krow + s * 32);
                floatx4 f1 = *(const floatx4*)(krow + s * 32 + 4);
                short8 kk;
                #pragma unroll
                for (int j = 0; j < 4; ++j) {
                    kk[j]     = (short)f32_to_bf16_bits(f0[j]);
                    kk[j + 4] = (short)f32_to_bf16_bits(f1[j]);
                }
                kf[s] = kk;
            }
        }
        intx4 mr[2];
        #pragma unroll
        for (int mt = 0; mt < 2; ++mt)
            mr[mt] = *(const intx4*)(mbase + (size_t)(mt * 16 + nl) * SEQ + k0 + w * 16 + quad * 4);

        floatx4 acc[2] = {{0.f,0.f,0.f,0.f},{0.f,0.f,0.f,0.f}};
        #pragma unroll
        for (int mt = 0; mt < 2; ++mt)
            #pragma unroll
            for (int s = 0; s < 2; ++s)
                acc[mt] = __builtin_amdgcn_mfma_f32_16x16x32_bf16(kf[s], aq[mt][s], acc[mt], 0, 0, 0);

        #pragma unroll
        for (int mt = 0; mt < 2; ++mt) {
            floatx4 sv;
            #pragma unroll
            for (int i = 0; i < 4; ++i) {
                float e = (mr[mt][i] != 0) ? __expf(acc[mt][i] * 0.125f) : 1.0f;
                sv[i] = e * rcp[mt];
            }
            *(floatx4*)&sb[(size_t)(mt * 16 + nl) * SEQ + k0 + w * 16 + quad * 4] = sv;
        }
    }
}

extern "C" void kernel_launch(void* const* d_in, const int* in_sizes, int n_in,
                              void* d_out, int out_size, void* d_ws, size_t ws_size,
                              hipStream_t stream) {
    (void)in_sizes; (void)n_in; (void)out_size; (void)d_ws; (void)ws_size;
    const float* q    = (const float*)d_in[0];
    const float* k    = (const float*)d_in[1];
    const float* v    = (const float*)d_in[2];
    const int*   mask = (const int*)d_in[3];
    float* out   = (float*)d_out;
    float* score = out + (size_t)BATCH * HEADS * SEQ * DIM;   // outputs concatenated: [out | score]
    dim3 grid(SEQ / QT, BATCH * HEADS);
    attn_fused_kernel<<<grid, dim3(256), 0, stream>>>(q, k, v, mask, out, score);
}

// Round 2
// 1685.108 us; speedup vs baseline: 1.2648x; 1.0723x over previous
//
#include <hip/hip_runtime.h>
#include <stdint.h>

#define BATCH 4
#define HEADS 16
#define SEQ   2048
#define DIM   64
#define QT    64            // q rows per workgroup (4 MFMA m-tiles)
#define MT    4             // QT/16
#define KT    64            // k cols per tile (16 per wave)
#define EST   72            // Es row stride elems: 144 B, 16B-aligned

typedef __attribute__((ext_vector_type(8))) short  short8;   // MFMA A/B frag (8 bf16)
typedef __attribute__((ext_vector_type(4))) short  short4v;  // b64 LDS store
typedef __attribute__((ext_vector_type(4))) float  floatx4;  // MFMA C/D frag / vector IO
typedef __attribute__((ext_vector_type(4))) int    intx4;

static __device__ __forceinline__ unsigned short f32_to_bf16_bits(float f) {
    union { float f; uint32_t u; } x; x.f = f;
    uint32_t r = x.u + 0x7FFFu + ((x.u >> 16) & 1u);   // RNE
    return (unsigned short)(r >> 16);
}

// ---------- prepass: K -> bf16 [bh][k][d]; V -> bf16 transposed [bh][d][k] ----------
__global__ __launch_bounds__(256) void prepass_kernel(
    const float* __restrict__ k, const float* __restrict__ v,
    unsigned short* __restrict__ kbf, unsigned short* __restrict__ vt)
{
    __shared__ unsigned short T[64][72];   // V^T staging tile (bf16), padded
    const int tid = threadIdx.x;
    const int r   = tid >> 2;          // 0..63
    const int cb  = (tid & 3) * 16;    // 0,16,32,48
    const int k0  = blockIdx.x * 64;
    const int bh  = blockIdx.y;

    const size_t rowoff = ((size_t)bh * SEQ + k0 + r) * DIM + cb;

    // K: straight convert, coalesced
    {
        const floatx4* kp = (const floatx4*)(k + rowoff);
        floatx4 f0 = kp[0], f1 = kp[1], f2 = kp[2], f3 = kp[3];
        short8 o0, o1;
        #pragma unroll
        for (int j = 0; j < 4; ++j) {
            o0[j]     = (short)f32_to_bf16_bits(f0[j]);
            o0[j + 4] = (short)f32_to_bf16_bits(f1[j]);
            o1[j]     = (short)f32_to_bf16_bits(f2[j]);
            o1[j + 4] = (short)f32_to_bf16_bits(f3[j]);
        }
        *(short8*)&kbf[rowoff]     = o0;
        *(short8*)&kbf[rowoff + 8] = o1;
    }
    // V: convert + transpose through LDS
    {
        const floatx4* vp = (const floatx4*)(v + rowoff);
        floatx4 f0 = vp[0], f1 = vp[1], f2 = vp[2], f3 = vp[3];
        #pragma unroll
        for (int j = 0; j < 4; ++j) {
            T[cb + j][r]      = f32_to_bf16_bits(f0[j]);
            T[cb + 4 + j][r]  = f32_to_bf16_bits(f1[j]);
            T[cb + 8 + j][r]  = f32_to_bf16_bits(f2[j]);
            T[cb + 12 + j][r] = f32_to_bf16_bits(f3[j]);
        }
    }
    __syncthreads();
    {
        // write V^T rows: d = r, k = k0+cb..cb+15  (coalesced 32B/thread)
        short8 t0 = *(const short8*)&T[r][cb];
        short8 t1 = *(const short8*)&T[r][cb + 8];
        unsigned short* dst = vt + ((size_t)bh * DIM + r) * SEQ + k0 + cb;
        *(short8*)dst       = t0;
        *(short8*)(dst + 8) = t1;
    }
}

// ---------- main fused kernel ----------
template <bool PRE>
__global__ __launch_bounds__(256, 4) void attn_fused_kernel(
    const float* __restrict__ q, const float* __restrict__ k,
    const float* __restrict__ v, const int* __restrict__ mask,
    const unsigned short* __restrict__ kbf, const unsigned short* __restrict__ vt,
    float* __restrict__ out, float* __restrict__ score)
{
    // Tiny double-buffered E bridge (QK^T C-frag -> PV B-frag). 18.4 KB.
    __shared__ __align__(16) unsigned short Es[2][QT][EST];
    __shared__ float lsum[QT];

    const int tid  = threadIdx.x;
    const int w    = tid >> 6;        // wave 0..3 -> 16-col k-slice of the 64-wide tile
    const int lane = tid & 63;
    const int quad = lane >> 4;       // 0..3
    const int nl   = lane & 15;

    const int qt = blockIdx.x;        // 0..31  (q tile)
    const int bh = blockIdx.y;        // 0..63  (b*H+h)
    const int b  = bh >> 4;           // H = 16
    const int q0 = qt * QT;

    const float* kbase = k + (size_t)bh * SEQ * DIM;
    const float* vbase = v + (size_t)bh * SEQ * DIM;
    const unsigned short* kbbase = PRE ? kbf + ((size_t)bh * SEQ + w * 16 + nl) * DIM + quad * 8 : nullptr;
    const unsigned short* vtbase = PRE ? vt + ((size_t)bh * DIM + w * 16 + nl) * SEQ + quad * 8 : nullptr;
    const int* mbase = mask + ((size_t)b * SEQ + q0) * SEQ;

    if (tid < QT) lsum[tid] = 0.0f;

    // ---- Q B-fragments once per block: aq[mt][s][j] = Q[q0+mt*16+nl][s*32+quad*8+j] ----
    short8 aq[MT][2];
    {
        const float* qp = q + ((size_t)bh * SEQ + q0) * DIM;
        #pragma unroll
        for (int mt = 0; mt < MT; ++mt) {
            const float* qrow = qp + (size_t)(mt * 16 + nl) * DIM + quad * 8;
            #pragma unroll
            for (int s = 0; s < 2; ++s) {
                floatx4 f0 = *(const floatx4*)(qrow + s * 32);
                floatx4 f1 = *(const floatx4*)(qrow + s * 32 + 4);
                short8 a;
                #pragma unroll
                for (int j = 0; j < 4; ++j) {
                    a[j]     = (short)f32_to_bf16_bits(f0[j]);
                    a[j + 4] = (short)f32_to_bf16_bits(f1[j]);
                }
                aq[mt][s] = a;
            }
        }
    }

    float   rs[MT]   = {0.f, 0.f, 0.f, 0.f};
    floatx4 oacc[MT] = {{0.f,0.f,0.f,0.f},{0.f,0.f,0.f,0.f},{0.f,0.f,0.f,0.f},{0.f,0.f,0.f,0.f}};

    // ============ Pass 1: fused QK^T -> exp -> PV (unnormalized) + rowsums ============
    for (int t = 0; t < SEQ / KT; ++t) {
        const int k0 = t * KT;
        const int p  = t & 1;

        // K frags: kf[s][j] = K[k0+w*16+nl][s*32+quad*8+j]
        short8 kf[2];
        if constexpr (PRE) {
            const unsigned short* kp = kbbase + (size_t)k0 * DIM;
            kf[0] = *(const short8*)kp;
            kf[1] = *(const short8*)(kp + 32);
        } else {
            const float* krow = kbase + (size_t)(k0 + w * 16 + nl) * DIM + quad * 8;
            #pragma unroll
            for (int s = 0; s < 2; ++s) {
                floatx4 f0 = *(const floatx4*)(krow + s * 32);
                floatx4 f1 = *(const floatx4*)(krow + s * 32 + 4);
                short8 kk;
                #pragma unroll
                for (int j = 0; j < 4; ++j) {
                    kk[j]     = (short)f32_to_bf16_bits(f0[j]);
                    kk[j + 4] = (short)f32_to_bf16_bits(f1[j]);
                }
                kf[s] = kk;
            }
        }
        // V frags: vf[s][j] = V[k0+s*32+quad*8+j][w*16+nl]
        short8 vf[2];
        if constexpr (PRE) {
            const unsigned short* vp = vtbase + k0;
            vf[0] = *(const short8*)vp;
            vf[1] = *(const short8*)(vp + 32);
        } else {
            const float* vp = vbase + ((size_t)k0 + quad * 8) * DIM + w * 16 + nl;
            #pragma unroll
            for (int s = 0; s < 2; ++s) {
                short8 vv;
                #pragma unroll
                for (int j = 0; j < 8; ++j)
                    vv[j] = (short)f32_to_bf16_bits(vp[(s * 32 + j) * DIM]);
                vf[s] = vv;
            }
        }

        // mask: int4 per row (4 consecutive k)
        intx4 mr[MT];
        #pragma unroll
        for (int mt = 0; mt < MT; ++mt)
            mr[mt] = *(const intx4*)(mbase + (size_t)(mt * 16 + nl) * SEQ + k0 + w * 16 + quad * 4);

        // Swapped QK^T: lane holds S[q=mt*16+nl][k=k0+w*16+quad*4+i]
        floatx4 acc[MT] = {{0.f,0.f,0.f,0.f},{0.f,0.f,0.f,0.f},{0.f,0.f,0.f,0.f},{0.f,0.f,0.f,0.f}};
        #pragma unroll
        for (int mt = 0; mt < MT; ++mt)
            #pragma unroll
            for (int s = 0; s < 2; ++s)
                acc[mt] = __builtin_amdgcn_mfma_f32_16x16x32_bf16(kf[s], aq[mt][s], acc[mt], 0, 0, 0);

        // E = exp(masked score), rowsum accumulate, stash bf16 tile (b64 stores)
        #pragma unroll
        for (int mt = 0; mt < MT; ++mt) {
            short4v es;
            float esum = 0.f;
            #pragma unroll
            for (int i = 0; i < 4; ++i) {
                float e = (mr[mt][i] != 0) ? __expf(acc[mt][i] * 0.125f) : 1.0f;  // exp(1e-12)==1.0f
                esum += e;
                es[i] = (short)f32_to_bf16_bits(e);
            }
            rs[mt] += esum;
            *(short4v*)&Es[p][mt * 16 + nl][w * 16 + quad * 4] = es;
        }

        __syncthreads();   // Es[p] complete; single barrier/tile (buffers alternate)

        // PV: O += V^T(A-frag) x E(B-frag);  lane gets O[q=mt*16+nl][d=w*16+quad*4+i]
        #pragma unroll
        for (int s = 0; s < 2; ++s)
            #pragma unroll
            for (int mt = 0; mt < MT; ++mt) {
                short8 ef = *(const short8*)&Es[p][mt * 16 + nl][s * 32 + quad * 8];
                oacc[mt] = __builtin_amdgcn_mfma_f32_16x16x32_bf16(vf[s], ef, oacc[mt], 0, 0, 0);
            }
    }

    // ============ rowsum -> reciprocal ============
    #pragma unroll
    for (int mt = 0; mt < MT; ++mt) {
        float x = rs[mt];
        x += __shfl_xor(x, 16);   // sum across quads
        x += __shfl_xor(x, 32);
        if (quad == 0) atomicAdd(&lsum[mt * 16 + nl], x);   // one add per wave per row
    }
    __syncthreads();
    if (tid < QT) lsum[tid] = 1.0f / lsum[tid];
    __syncthreads();
    const float rcp[MT] = { lsum[nl], lsum[16 + nl], lsum[32 + nl], lsum[48 + nl] };

    // ============ O write: float4 per mt ============
    #pragma unroll
    for (int mt = 0; mt < MT; ++mt) {
        floatx4 o;
        #pragma unroll
        for (int i = 0; i < 4; ++i) o[i] = oacc[mt][i] * rcp[mt];
        *(floatx4*)&out[((size_t)bh * SEQ + q0 + mt * 16 + nl) * DIM + w * 16 + quad * 4] = o;
    }

    // ============ Pass 2: recompute E, write normalized score (barrier-free stream) ============
    float* sb = score + ((size_t)bh * SEQ + q0) * SEQ;
    for (int t = 0; t < SEQ / KT; ++t) {
        const int k0 = t * KT;

        short8 kf[2];
        if constexpr (PRE) {
            const unsigned short* kp = kbbase + (size_t)k0 * DIM;
            kf[0] = *(const short8*)kp;
            kf[1] = *(const short8*)(kp + 32);
        } else {
            const float* krow = kbase + (size_t)(k0 + w * 16 + nl) * DIM + quad * 8;
            #pragma unroll
            for (int s = 0; s < 2; ++s) {
                floatx4 f0 = *(const floatx4*)(krow + s * 32);
                floatx4 f1 = *(const floatx4*)(krow + s * 32 + 4);
                short8 kk;
                #pragma unroll
                for (int j = 0; j < 4; ++j) {
                    kk[j]     = (short)f32_to_bf16_bits(f0[j]);
                    kk[j + 4] = (short)f32_to_bf16_bits(f1[j]);
                }
                kf[s] = kk;
            }
        }
        intx4 mr[MT];
        #pragma unroll
        for (int mt = 0; mt < MT; ++mt)
            mr[mt] = *(const intx4*)(mbase + (size_t)(mt * 16 + nl) * SEQ + k0 + w * 16 + quad * 4);

        floatx4 acc[MT] = {{0.f,0.f,0.f,0.f},{0.f,0.f,0.f,0.f},{0.f,0.f,0.f,0.f},{0.f,0.f,0.f,0.f}};
        #pragma unroll
        for (int mt = 0; mt < MT; ++mt)
            #pragma unroll
            for (int s = 0; s < 2; ++s)
                acc[mt] = __builtin_amdgcn_mfma_f32_16x16x32_bf16(kf[s], aq[mt][s], acc[mt], 0, 0, 0);

        #pragma unroll
        for (int mt = 0; mt < MT; ++mt) {
            floatx4 sv;
            #pragma unroll
            for (int i = 0; i < 4; ++i) {
                float e = (mr[mt][i] != 0) ? __expf(acc[mt][i] * 0.125f) : 1.0f;
                sv[i] = e * rcp[mt];
            }
            *(floatx4*)&sb[(size_t)(mt * 16 + nl) * SEQ + k0 + w * 16 + quad * 4] = sv;
        }
    }
}

extern "C" void kernel_launch(void* const* d_in, const int* in_sizes, int n_in,
                              void* d_out, int out_size, void* d_ws, size_t ws_size,
                              hipStream_t stream) {
    (void)in_sizes; (void)n_in; (void)out_size;
    const float* q    = (const float*)d_in[0];
    const float* k    = (const float*)d_in[1];
    const float* v    = (const float*)d_in[2];
    const int*   mask = (const int*)d_in[3];
    float* out   = (float*)d_out;
    float* score = out + (size_t)BATCH * HEADS * SEQ * DIM;   // outputs concatenated: [out | score]

    const size_t elems = (size_t)BATCH * HEADS * SEQ * DIM;
    const size_t need  = elems * 2 * 2;                       // Kbf + Vt, bf16
    dim3 grid(SEQ / QT, BATCH * HEADS);

    if (d_ws != nullptr && ws_size >= need) {
        unsigned short* kbf = (unsigned short*)d_ws;
        unsigned short* vtp = kbf + elems;
        prepass_kernel<<<dim3(SEQ / 64, BATCH * HEADS), dim3(256), 0, stream>>>(k, v, kbf, vtp);
        attn_fused_kernel<true><<<grid, dim3(256), 0, stream>>>(q, k, v, mask, kbf, vtp, out, score);
    } else {
        attn_fused_kernel<false><<<grid, dim3(256), 0, stream>>>(q, k, v, mask, nullptr, nullptr, out, score);
    }
}